// Round 3
// baseline (554.732 us; speedup 1.0000x reference)
//
#include <hip/hip_runtime.h>
#include <math.h>

#define N_NODES 50000
#define N_EDGES 800000
#define D 128
#define N_LAYERS 3

#define FCHUNK 2048                              // edges per fill chunk
#define NCHUNK ((N_EDGES + FCHUNK - 1) / FCHUNK) // 391
#define GDIV 6250                                // src-ids per XCD group (8 groups)
#define SLOT 96                                  // csr slots per node (deg ~ Poisson(16))
#define PREPB ((N_LAYERS * D * D) / 256)         // 192 blocks for prep_w
#define LINB ((N_NODES + 63) / 64)               // 782 linear blocks

// sliced gather: 8 slices x 16 dims; slice s -> XCD s via blockIdx&7
#define SLICE_ELEMS (N_NODES * 16)               // elems per slice plane (800k)
#define NPW 5                                    // nodes per wave in gather
#define NGRP (N_NODES / (4 * NPW))               // 2500 groups
#define GBLK (NGRP * 8)                          // 20000 gather blocks

typedef _Float16 half8 __attribute__((ext_vector_type(8)));
typedef _Float16 half4 __attribute__((ext_vector_type(4)));
typedef float f32x4 __attribute__((ext_vector_type(4)));

// ---------------------------------------------------------------------------
// W prep (own kernel, launched first): Wt16[l][n][k] = (f16) W[l][k][n].
// ---------------------------------------------------------------------------
__global__ __launch_bounds__(256) void prep_w_kernel(
    const float* __restrict__ W, _Float16* __restrict__ Wt)
{
    int idx = blockIdx.x * 256 + threadIdx.x;
    int l = idx >> 14, rem = idx & (D * D - 1);
    int k = rem >> 7, n = rem & 127;
    Wt[l * D * D + n * D + k] = (_Float16)W[idx];
}

// ---------------------------------------------------------------------------
// MFMA linear + fused sr:  hout = leaky_relu(A @ W + b);  sr[n] = hout[n].awr
// Block = 4 waves x 16 rows. Full W^T in LDS (stride 130).
// hout is SLICE-MAJOR: hout[s][n][16] (s = col/16). The t-loop below maps
// 1:1 onto slices, and 16 m-lanes give 32B-contiguous stores per (t,row).
// F16 A-load reads slice-major too (row stride 32B -> better coalescing).
// FUSEFILL (layer 0 only): blocks >= LINB run the XCD-partitioned CSR fill
// (no data dependence on the linear part, hides fill under linear_0).
// ---------------------------------------------------------------------------
template <bool F32IN, bool FUSEFILL>
__global__ __launch_bounds__(256) void linear_mfma_kernel(
    const void* __restrict__ Ain, const _Float16* __restrict__ Wt,
    const float* __restrict__ b, const float* __restrict__ awr,
    _Float16* __restrict__ hout, float* __restrict__ sr,
    const int* __restrict__ esrc, const int* __restrict__ edst,
    int* __restrict__ cnt, unsigned short* __restrict__ csr16)
{
    __shared__ _Float16 Wl[D * 130];

    if (FUSEFILL && blockIdx.x >= LINB) {
        int fi = blockIdx.x - LINB;
        int g = blockIdx.x & 7;
        int base = (fi >> 3) * FCHUNK;
        int ecnt = N_EDGES - base;
        if (ecnt > FCHUNK) ecnt = FCHUNK;
        unsigned glo = (unsigned)(g * GDIV);
        for (int i = threadIdx.x * 4; i < ecnt; i += 1024) {
            int4 s4 = *(const int4*)(esrc + base + i);
            int4 d4 = *(const int4*)(edst + base + i);
            int ss[4] = {s4.x, s4.y, s4.z, s4.w};
            int dd[4] = {d4.x, d4.y, d4.z, d4.w};
#pragma unroll
            for (int j = 0; j < 4; ++j) {
                if ((unsigned)ss[j] - glo < (unsigned)GDIV) {
                    int pos = atomicAdd(cnt + ss[j], 1);
                    if (pos < SLOT)
                        csr16[(size_t)ss[j] * SLOT + pos] = (unsigned short)dd[j];
                }
            }
        }
        return;
    }

    int tid = threadIdx.x;
    for (int j = tid * 8; j < D * D; j += 2048) {
        int n = j >> 7, k = j & 127;
        *(half8*)(&Wl[n * 130 + k]) = *(const half8*)(Wt + j);
    }
    __syncthreads();

    int wid = tid >> 6, lane = tid & 63;
    int m = lane & 15, q = lane >> 4;
    int rowbase = blockIdx.x * 64 + wid * 16;
    int row = rowbase + m;

    half8 a[4];
    if (row < N_NODES) {
        if (F32IN) {
            const float* ar = (const float*)Ain + (size_t)row * D;
#pragma unroll
            for (int s = 0; s < 4; ++s) {
                float4 lo = *(const float4*)(ar + s * 32 + q * 8);
                float4 hi = *(const float4*)(ar + s * 32 + q * 8 + 4);
                a[s][0] = (_Float16)lo.x; a[s][1] = (_Float16)lo.y;
                a[s][2] = (_Float16)lo.z; a[s][3] = (_Float16)lo.w;
                a[s][4] = (_Float16)hi.x; a[s][5] = (_Float16)hi.y;
                a[s][6] = (_Float16)hi.z; a[s][7] = (_Float16)hi.w;
            }
        } else {
            // slice-major input: dim block s*32+q*8 lives in slice 2s+(q>>1)
            const _Float16* ar = (const _Float16*)Ain;
#pragma unroll
            for (int s = 0; s < 4; ++s) {
                int sl = 2 * s + (q >> 1);
                a[s] = *(const half8*)(ar + (size_t)sl * SLICE_ELEMS + row * 16 + (q & 1) * 8);
            }
        }
    } else {
#pragma unroll
        for (int s = 0; s < 4; ++s)
#pragma unroll
            for (int j = 0; j < 8; ++j) a[s][j] = (_Float16)0.f;
    }

    f32x4 acc[8];
#pragma unroll
    for (int t = 0; t < 8; ++t) acc[t] = (f32x4)(0.f);

#pragma unroll
    for (int s = 0; s < 4; ++s) {
#pragma unroll
        for (int t = 0; t < 8; ++t) {
            half8 bf = *(const half8*)(&Wl[(t * 16 + m) * 130 + s * 32 + q * 8]);
            acc[t] = __builtin_amdgcn_mfma_f32_16x16x32_f16(a[s], bf, acc[t], 0, 0, 0);
        }
    }

    float sp[4] = {0.f, 0.f, 0.f, 0.f};
#pragma unroll
    for (int t = 0; t < 8; ++t) {
        int col = t * 16 + m;
        float bc = b[col];
        float ac = awr[col];
#pragma unroll
        for (int r = 0; r < 4; ++r) {
            int orow = rowbase + q * 4 + r;
            float v = acc[t][r] + bc;
            v = v > 0.f ? v : 0.2f * v;
            sp[r] = fmaf(v, ac, sp[r]);
            if (orow < N_NODES)
                hout[(size_t)t * SLICE_ELEMS + orow * 16 + m] = (_Float16)v;
        }
    }
#pragma unroll
    for (int r = 0; r < 4; ++r) {
#pragma unroll
        for (int o = 1; o < 16; o <<= 1)
            sp[r] += __shfl_xor(sp[r], o, 64);
    }
    if (m == 0) {
#pragma unroll
        for (int r = 0; r < 4; ++r) {
            int orow = rowbase + q * 4 + r;
            if (orow < N_NODES) sr[orow] = sp[r];
        }
    }
}

// ---------------------------------------------------------------------------
// XCD-sliced softmax+gather. Block s=blockIdx&7 handles slice s (16 dims,
// 1.6 MB slice-major sub-table -> resident in XCD s's L2). Softmax is
// recomputed per slice (sr is 200KB, L2-resident; exp is cheap) so no alpha
// buffer is needed. Wave layout: edge-slot e=lane>>2 (16 edges in flight),
// dim-quad c=lane&3 (8B half4 per lane, 32B per edge = 1 cache line).
// deg capped at 64 (P(deg>64) ~ 1e-20 for Poisson(16)).
// ---------------------------------------------------------------------------
__global__ __launch_bounds__(256) void gather_sliced_kernel(
    const int* __restrict__ cnt, const unsigned short* __restrict__ csr16,
    const float* __restrict__ sr, const _Float16* __restrict__ h,
    _Float16* __restrict__ out16, float* __restrict__ out32)
{
    int s = blockIdx.x & 7;
    int grp = blockIdx.x >> 3;
    int wid = threadIdx.x >> 6, lane = threadIdx.x & 63;
    int e = lane >> 2, c = lane & 3;
    const _Float16* hs = h + (size_t)s * SLICE_ELEMS;
    int nbase = grp * (4 * NPW) + wid * NPW;

    for (int nn = 0; nn < NPW; ++nn) {
        int n = nbase + nn;
        if (n >= N_NODES) break;
        int deg = cnt[n];
        if (deg > 64) deg = 64;
        const unsigned short* ce = csr16 + (size_t)n * SLOT;

        int dl = 0;
        float ev = -INFINITY;
        if (lane < deg) { dl = ce[lane]; ev = sr[dl]; }
        float m = ev;
        for (int o = 32; o > 0; o >>= 1) m = fmaxf(m, __shfl_xor(m, o, 64));
        float a = (lane < deg) ? __expf(ev - m) : 0.f;
        float ssum = a;
        for (int o = 32; o > 0; o >>= 1) ssum += __shfl_xor(ssum, o, 64);
        float al = (deg > 0) ? a / ssum : 0.f;  // normalized alpha, lane-held

        float acc0 = 0.f, acc1 = 0.f, acc2 = 0.f, acc3 = 0.f;
        for (int k = 0; k < deg; k += 16) {
            int es = k + e;                       // <= 63
            int d = __shfl(dl, es, 64);
            float av = __shfl(al, es, 64);        // 0 for es >= deg
            half4 hv = *(const half4*)(hs + (size_t)d * 16 + c * 4);
            acc0 = fmaf((float)hv[0], av, acc0);
            acc1 = fmaf((float)hv[1], av, acc1);
            acc2 = fmaf((float)hv[2], av, acc2);
            acc3 = fmaf((float)hv[3], av, acc3);
        }
#pragma unroll
        for (int o = 4; o < 64; o <<= 1) {
            acc0 += __shfl_xor(acc0, o, 64);
            acc1 += __shfl_xor(acc1, o, 64);
            acc2 += __shfl_xor(acc2, o, 64);
            acc3 += __shfl_xor(acc3, o, 64);
        }
        if (e == 0) {                             // lanes 0..3
            float r0 = fmaxf(acc0, 0.f);
            float r1 = fmaxf(acc1, 0.f);
            float r2 = fmaxf(acc2, 0.f);
            float r3 = fmaxf(acc3, 0.f);
            if (out16) {
                half4 o4;
                o4[0] = (_Float16)r0; o4[1] = (_Float16)r1;
                o4[2] = (_Float16)r2; o4[3] = (_Float16)r3;
                *(half4*)(out16 + (size_t)s * SLICE_ELEMS + n * 16 + c * 4) = o4;
            } else {
                float4 o4 = make_float4(r0, r1, r2, r3);
                *(float4*)(out32 + (size_t)n * D + s * 16 + c * 4) = o4;
            }
        }
    }
}

extern "C" void kernel_launch(void* const* d_in, const int* in_sizes, int n_in,
                              void* d_out, int out_size, void* d_ws, size_t ws_size,
                              hipStream_t stream)
{
    const float* x      = (const float*)d_in[0];
    const int*   esrc   = (const int*)d_in[1];
    const int*   edst   = (const int*)d_in[2];
    const float* lin_w  = (const float*)d_in[3];
    const float* lin_b  = (const float*)d_in[4];
    const float* attn_w = (const float*)d_in[5];
    float* out = (float*)d_out;

    char* ws = (char*)d_ws;
    _Float16*       h16A  = (_Float16*)(ws);                  // 12,800,000 B (slice-major)
    _Float16*       h16B  = (_Float16*)(ws + 12800000);       // 12,800,000 B (slice-major)
    float*          sr    = (float*)(ws + 25600000);          // 200,000 B
    int*            cnt   = (int*)(ws + 25800000);            // 200,000 B
    unsigned short* csr16 = (unsigned short*)(ws + 26000000); // 9,600,000 B
    _Float16*       Wt16  = (_Float16*)(ws + 35600000);       // 98,304 B

    // Zero degree counters, convert W (tiny), then fused linear_0 + CSR fill.
    hipMemsetAsync(cnt, 0, N_NODES * sizeof(int), stream);
    prep_w_kernel<<<PREPB, 256, 0, stream>>>(lin_w, Wt16);

    for (int l = 0; l < N_LAYERS; ++l) {
        bool last = (l == N_LAYERS - 1);
        if (l == 0)
            linear_mfma_kernel<true, true><<<LINB + NCHUNK * 8, 256, 0, stream>>>(
                x, Wt16, lin_b, attn_w + D, h16A, sr,
                esrc, edst, cnt, csr16);
        else
            linear_mfma_kernel<false, false><<<LINB, 256, 0, stream>>>(
                h16B, Wt16 + (size_t)l * D * D, lin_b + (size_t)l * D,
                attn_w + (size_t)l * 2 * D + D, h16A, sr,
                nullptr, nullptr, nullptr, nullptr);
        gather_sliced_kernel<<<GBLK, 256, 0, stream>>>(
            cnt, csr16, sr, h16A,
            last ? (_Float16*)nullptr : h16B, last ? out : nullptr);
    }
}

// Round 5
// 268.256 us; speedup vs baseline: 2.0679x; 2.0679x over previous
//
#include <hip/hip_runtime.h>
#include <math.h>

#define N_NODES 50000
#define N_EDGES 800000
#define D 128
#define N_LAYERS 3

#define FCHUNK 4096                              // edges per fill chunk (16/thread)
#define NCHUNK ((N_EDGES + FCHUNK - 1) / FCHUNK) // 196
#define GDIV 6250                                // src-ids per XCD group (8 groups)
#define SLOT 96                                  // csr slots per node (deg ~ Poisson(16))
#define PREPB ((N_LAYERS * D * D) / 256)         // 192 blocks for prep_w
#define LINB ((N_NODES + 63) / 64)               // 782 linear blocks

typedef _Float16 half8 __attribute__((ext_vector_type(8)));
typedef _Float16 half4 __attribute__((ext_vector_type(4)));
typedef float f32x4 __attribute__((ext_vector_type(4)));

// ---------------------------------------------------------------------------
// Fixed-slot CSR fill + W prep. NO LDS and __launch_bounds__(256,8) so the
// latency-bound atomic fill runs at up to 8 blocks/CU (round-2's fusion into
// the 33KB-LDS linear kernel capped it at 4/CU -> 35% occupancy, 49us with
// nothing busy). FCHUNK=4096 -> 16 edges scanned/thread -> ~2 independent
// atomics in flight per thread (ILP for the atomic latency chain).
// Blocks [0, NCHUNK*8): XCD-partitioned fill — block (chunk c=blk>>3,
// group g=blk&7) handles chunk-c edges with src in [g*GDIV,(g+1)*GDIV) so
// cnt atomics + csr16 stores for a line come from one XCD.
// Blocks [NCHUNK*8, +PREPB): Wt16[l][n][k] = (f16) W[l][k][n].
// ---------------------------------------------------------------------------
__global__ __launch_bounds__(256, 8) void fill_prep_kernel(
    const int* __restrict__ src, const int* __restrict__ dst,
    int* __restrict__ cnt, unsigned short* __restrict__ csr16,
    const float* __restrict__ W, _Float16* __restrict__ Wt)
{
    if (blockIdx.x >= NCHUNK * 8) {
        int idx = (blockIdx.x - NCHUNK * 8) * 256 + threadIdx.x;
        int l = idx >> 14, rem = idx & (D * D - 1);
        int k = rem >> 7, n = rem & 127;
        Wt[l * D * D + n * D + k] = (_Float16)W[idx];
        return;
    }
    int g = blockIdx.x & 7;
    int base = (blockIdx.x >> 3) * FCHUNK;
    int ecnt = N_EDGES - base;
    if (ecnt > FCHUNK) ecnt = FCHUNK;
    unsigned glo = (unsigned)(g * GDIV);
    for (int i = threadIdx.x * 4; i < ecnt; i += 1024) {
        int4 s4 = *(const int4*)(src + base + i);
        int4 d4 = *(const int4*)(dst + base + i);
        int ss[4] = {s4.x, s4.y, s4.z, s4.w};
        int dd[4] = {d4.x, d4.y, d4.z, d4.w};
#pragma unroll
        for (int j = 0; j < 4; ++j) {
            if ((unsigned)ss[j] - glo < (unsigned)GDIV) {
                int pos = atomicAdd(cnt + ss[j], 1);
                if (pos < SLOT) csr16[(size_t)ss[j] * SLOT + pos] = (unsigned short)dd[j];
            }
        }
    }
}

// ---------------------------------------------------------------------------
// MFMA linear + fused sr:  hout = leaky_relu(A @ W + b);  sr[n] = hout[n].awr
// Block = 4 waves x 16 rows. Full W^T in LDS (stride 130). Row-major h.
// ---------------------------------------------------------------------------
template <bool F32IN>
__global__ __launch_bounds__(256) void linear_mfma_kernel(
    const void* __restrict__ Ain, const _Float16* __restrict__ Wt,
    const float* __restrict__ b, const float* __restrict__ awr,
    _Float16* __restrict__ hout, float* __restrict__ sr)
{
    __shared__ _Float16 Wl[D * 130];
    int tid = threadIdx.x;
    for (int j = tid * 8; j < D * D; j += 2048) {
        int n = j >> 7, k = j & 127;
        *(half8*)(&Wl[n * 130 + k]) = *(const half8*)(Wt + j);
    }
    __syncthreads();

    int wid = tid >> 6, lane = tid & 63;
    int m = lane & 15, q = lane >> 4;
    int rowbase = blockIdx.x * 64 + wid * 16;
    int row = rowbase + m;

    half8 a[4];
    if (row < N_NODES) {
        if (F32IN) {
            const float* ar = (const float*)Ain + (size_t)row * D;
#pragma unroll
            for (int s = 0; s < 4; ++s) {
                float4 lo = *(const float4*)(ar + s * 32 + q * 8);
                float4 hi = *(const float4*)(ar + s * 32 + q * 8 + 4);
                a[s][0] = (_Float16)lo.x; a[s][1] = (_Float16)lo.y;
                a[s][2] = (_Float16)lo.z; a[s][3] = (_Float16)lo.w;
                a[s][4] = (_Float16)hi.x; a[s][5] = (_Float16)hi.y;
                a[s][6] = (_Float16)hi.z; a[s][7] = (_Float16)hi.w;
            }
        } else {
            const _Float16* ar = (const _Float16*)Ain + (size_t)row * D;
#pragma unroll
            for (int s = 0; s < 4; ++s)
                a[s] = *(const half8*)(ar + s * 32 + q * 8);
        }
    } else {
#pragma unroll
        for (int s = 0; s < 4; ++s)
#pragma unroll
            for (int j = 0; j < 8; ++j) a[s][j] = (_Float16)0.f;
    }

    f32x4 acc[8];
#pragma unroll
    for (int t = 0; t < 8; ++t) acc[t] = (f32x4)(0.f);

#pragma unroll
    for (int s = 0; s < 4; ++s) {
#pragma unroll
        for (int t = 0; t < 8; ++t) {
            half8 bf = *(const half8*)(&Wl[(t * 16 + m) * 130 + s * 32 + q * 8]);
            acc[t] = __builtin_amdgcn_mfma_f32_16x16x32_f16(a[s], bf, acc[t], 0, 0, 0);
        }
    }

    float sp[4] = {0.f, 0.f, 0.f, 0.f};
#pragma unroll
    for (int t = 0; t < 8; ++t) {
        int col = t * 16 + m;
        float bc = b[col];
        float ac = awr[col];
#pragma unroll
        for (int r = 0; r < 4; ++r) {
            int orow = rowbase + q * 4 + r;
            float v = acc[t][r] + bc;
            v = v > 0.f ? v : 0.2f * v;
            sp[r] = fmaf(v, ac, sp[r]);
            if (orow < N_NODES)
                hout[(size_t)orow * D + col] = (_Float16)v;
        }
    }
#pragma unroll
    for (int r = 0; r < 4; ++r) {
#pragma unroll
        for (int o = 1; o < 16; o <<= 1)
            sp[r] += __shfl_xor(sp[r], o, 64);
    }
    if (m == 0) {
#pragma unroll
        for (int r = 0; r < 4; ++r) {
            int orow = rowbase + q * 4 + r;
            if (orow < N_NODES) sr[orow] = sp[r];
        }
    }
}

// ---------------------------------------------------------------------------
// Fused softmax + gather, one wave per node, h f16, fixed-slot csr u16.
// Dual-row: lanes 0-31 even edges, 32-63 odd edges; half4 (8B) per lane;
// unroll 8 edges -> 4 independent row loads in flight per half-wave.
// (byte-offset, alpha) pairs in LDS -> one ds_read_b64 per edge.
// ---------------------------------------------------------------------------
__global__ __launch_bounds__(256, 8) void gather_kernel(
    const int* __restrict__ cnt, const unsigned short* __restrict__ csr16,
    const float* __restrict__ sr, const _Float16* __restrict__ h,
    _Float16* __restrict__ out16, float* __restrict__ out32)
{
    __shared__ int plds[4][2 * SLOT + 8];
    int wid = threadIdx.x >> 6, lane = threadIdx.x & 63;
    int half = lane >> 5, sl = lane & 31;
    int n = blockIdx.x * 4 + wid;
    int deg = cnt[n];
    if (deg > SLOT) deg = SLOT;
    const unsigned short* ce = csr16 + (size_t)n * SLOT;
    int* prow = plds[wid];

    float ev[2];
    float m = -INFINITY;
#pragma unroll
    for (int t = 0; t < 2; ++t) {
        int k = t * 64 + lane;
        if (k < deg) {
            int d = ce[k];
            prow[2 * k] = d << 8;
            float e = sr[d];
            ev[t] = e;
            m = fmaxf(m, e);
        }
    }
    for (int o = 32; o > 0; o >>= 1) m = fmaxf(m, __shfl_xor(m, o, 64));

    float s = 0.f;
#pragma unroll
    for (int t = 0; t < 2; ++t) {
        int k = t * 64 + lane;
        if (k < deg) {
            float a = __expf(ev[t] - m);
            prow[2 * k + 1] = __float_as_int(a);
            s += a;
        }
    }
    for (int o = 32; o > 0; o >>= 1) s += __shfl_xor(s, o, 64);
    float inv = (deg > 0) ? 1.f / s : 0.f;

    float acc0 = 0.f, acc1 = 0.f, acc2 = 0.f, acc3 = 0.f;
    const char* hb = (const char*)h + sl * 8;
    int k = 0;
    int deg8 = deg & ~7;
    for (; k < deg8; k += 8) {
        int2 p0 = *(const int2*)(prow + 2 * (k + half));
        int2 p1 = *(const int2*)(prow + 2 * (k + 2 + half));
        int2 p2 = *(const int2*)(prow + 2 * (k + 4 + half));
        int2 p3 = *(const int2*)(prow + 2 * (k + 6 + half));
        half4 h0 = *(const half4*)(hb + p0.x);
        half4 h1 = *(const half4*)(hb + p1.x);
        half4 h2 = *(const half4*)(hb + p2.x);
        half4 h3 = *(const half4*)(hb + p3.x);
        float a0 = __int_as_float(p0.y);
        float a1 = __int_as_float(p1.y);
        float a2 = __int_as_float(p2.y);
        float a3 = __int_as_float(p3.y);
        acc0 = fmaf((float)h0[0], a0, acc0);
        acc1 = fmaf((float)h0[1], a0, acc1);
        acc2 = fmaf((float)h0[2], a0, acc2);
        acc3 = fmaf((float)h0[3], a0, acc3);
        acc0 = fmaf((float)h1[0], a1, acc0);
        acc1 = fmaf((float)h1[1], a1, acc1);
        acc2 = fmaf((float)h1[2], a1, acc2);
        acc3 = fmaf((float)h1[3], a1, acc3);
        acc0 = fmaf((float)h2[0], a2, acc0);
        acc1 = fmaf((float)h2[1], a2, acc1);
        acc2 = fmaf((float)h2[2], a2, acc2);
        acc3 = fmaf((float)h2[3], a2, acc3);
        acc0 = fmaf((float)h3[0], a3, acc0);
        acc1 = fmaf((float)h3[1], a3, acc1);
        acc2 = fmaf((float)h3[2], a3, acc2);
        acc3 = fmaf((float)h3[3], a3, acc3);
    }
    for (; k < deg; k += 2) {
        int kk = k + half;
        int2 p = (kk < deg) ? *(const int2*)(prow + 2 * kk) : make_int2(0, 0);
        half4 hv = *(const half4*)(hb + p.x);
        float a = __int_as_float(p.y);
        acc0 = fmaf((float)hv[0], a, acc0);
        acc1 = fmaf((float)hv[1], a, acc1);
        acc2 = fmaf((float)hv[2], a, acc2);
        acc3 = fmaf((float)hv[3], a, acc3);
    }

    acc0 += __shfl_xor(acc0, 32, 64);
    acc1 += __shfl_xor(acc1, 32, 64);
    acc2 += __shfl_xor(acc2, 32, 64);
    acc3 += __shfl_xor(acc3, 32, 64);

    if (half == 0) {
        float r0 = fmaxf(acc0 * inv, 0.f);
        float r1 = fmaxf(acc1 * inv, 0.f);
        float r2 = fmaxf(acc2 * inv, 0.f);
        float r3 = fmaxf(acc3 * inv, 0.f);
        if (out16) {
            half4 o;
            o[0] = (_Float16)r0; o[1] = (_Float16)r1;
            o[2] = (_Float16)r2; o[3] = (_Float16)r3;
            *(half4*)(out16 + (size_t)n * D + sl * 4) = o;
        } else {
            float4 o = make_float4(r0, r1, r2, r3);
            *(float4*)(out32 + (size_t)n * D + sl * 4) = o;
        }
    }
}

extern "C" void kernel_launch(void* const* d_in, const int* in_sizes, int n_in,
                              void* d_out, int out_size, void* d_ws, size_t ws_size,
                              hipStream_t stream)
{
    const float* x      = (const float*)d_in[0];
    const int*   esrc   = (const int*)d_in[1];
    const int*   edst   = (const int*)d_in[2];
    const float* lin_w  = (const float*)d_in[3];
    const float* lin_b  = (const float*)d_in[4];
    const float* attn_w = (const float*)d_in[5];
    float* out = (float*)d_out;

    char* ws = (char*)d_ws;
    _Float16*       h16A  = (_Float16*)(ws);                  // 12,800,000 B
    _Float16*       h16B  = (_Float16*)(ws + 12800000);       // 12,800,000 B
    float*          sr    = (float*)(ws + 25600000);          // 200,000 B
    int*            cnt   = (int*)(ws + 25800000);            // 200,000 B
    unsigned short* csr16 = (unsigned short*)(ws + 26000000); // 9,600,000 B
    _Float16*       Wt16  = (_Float16*)(ws + 35600000);       // 98,304 B

    // One-time prep: zero degree counters, then fused fill(CSR)+W-convert
    // at full occupancy (no LDS in this kernel).
    hipMemsetAsync(cnt, 0, N_NODES * sizeof(int), stream);
    fill_prep_kernel<<<NCHUNK * 8 + PREPB, 256, 0, stream>>>(
        esrc, edst, cnt, csr16, lin_w, Wt16);

    for (int l = 0; l < N_LAYERS; ++l) {
        const void* A = (l == 0) ? (const void*)x : (const void*)h16B;
        if (l == 0)
            linear_mfma_kernel<true><<<LINB, 256, 0, stream>>>(
                A, Wt16, lin_b, attn_w + D, h16A, sr);
        else
            linear_mfma_kernel<false><<<LINB, 256, 0, stream>>>(
                A, Wt16 + (size_t)l * D * D, lin_b + (size_t)l * D,
                attn_w + (size_t)l * 2 * D + D, h16A, sr);
        bool last = (l == N_LAYERS - 1);
        gather_kernel<<<N_NODES / 4, 256, 0, stream>>>(
            cnt, csr16, sr, h16A,
            last ? (_Float16*)nullptr : h16B, last ? out : nullptr);
    }
}

// Round 6
// 262.410 us; speedup vs baseline: 2.1140x; 1.0223x over previous
//
#include <hip/hip_runtime.h>
#include <math.h>

#define N_NODES 50000
#define N_EDGES 800000
#define D 128
#define N_LAYERS 3

#define FCHUNK 4096                              // edges per fill chunk (16/thread)
#define NCHUNK ((N_EDGES + FCHUNK - 1) / FCHUNK) // 196
#define GDIV 6250                                // src-ids per XCD group (8 groups)
#define SLOT 96                                  // csr slots per node (deg ~ Poisson(16))
#define PREPB ((N_LAYERS * D * D) / 256)         // 192 blocks for W transpose
#define CNTB ((N_NODES + 255) / 256)             // 196 blocks for cnt zero
#define LINB ((N_NODES + 63) / 64)               // 782 linear blocks

typedef _Float16 half8 __attribute__((ext_vector_type(8)));
typedef _Float16 half4 __attribute__((ext_vector_type(4)));
typedef float f32x4 __attribute__((ext_vector_type(4)));

// ---------------------------------------------------------------------------
// Prep: W transpose to f16 [l][n][k] + zero the degree counters (folded in
// to save a memset dispatch + launch gap).
// ---------------------------------------------------------------------------
__global__ __launch_bounds__(256) void prep_kernel(
    const float* __restrict__ W, _Float16* __restrict__ Wt, int* __restrict__ cnt)
{
    if (blockIdx.x < PREPB) {
        int idx = blockIdx.x * 256 + threadIdx.x;
        int l = idx >> 14, rem = idx & (D * D - 1);
        int k = rem >> 7, n = rem & 127;
        Wt[l * D * D + n * D + k] = (_Float16)W[idx];
    } else {
        int i = (blockIdx.x - PREPB) * 256 + threadIdx.x;
        if (i < N_NODES) cnt[i] = 0;
    }
}

// ---------------------------------------------------------------------------
// MFMA linear + fused sr:  hout = leaky_relu(A @ W + b);  sr[n] = hout[n].awr
// Block = 4 waves x 16 rows. W^T staged in TWO 64-col halves (16.6 KB LDS,
// vs 33 KB full-W in round 2) so the kernel runs at 6 blocks/CU instead of
// 4 — round-2's fused fill+linear measured 49us @ 35% occupancy with nothing
// busy (latency-bound); the LDS cap was the occupancy limiter.
// FUSEFILL (layer 0): blocks >= LINB run the XCD-partitioned CSR fill (no
// data dependence on the linear part; fill cost hides under linear_0).
// Fill chunk c occupies consecutive global blocks LINB+8c..LINB+8c+7, so
// g = blockIdx.x & 7 covers each (chunk, XCD-group) pair exactly once.
// ---------------------------------------------------------------------------
template <bool F32IN, bool FUSEFILL>
__global__ __launch_bounds__(256, 6) void linear_mfma_kernel(
    const void* __restrict__ Ain, const _Float16* __restrict__ Wt,
    const float* __restrict__ b, const float* __restrict__ awr,
    _Float16* __restrict__ hout, float* __restrict__ sr,
    const int* __restrict__ esrc, const int* __restrict__ edst,
    int* __restrict__ cnt, unsigned short* __restrict__ csr16)
{
    __shared__ _Float16 Wl[64 * 130];  // 16,640 B

    if (FUSEFILL && blockIdx.x >= LINB) {
        int g = blockIdx.x & 7;
        int base = ((blockIdx.x - LINB) >> 3) * FCHUNK;
        int ecnt = N_EDGES - base;
        if (ecnt > FCHUNK) ecnt = FCHUNK;
        unsigned glo = (unsigned)(g * GDIV);
        for (int i = threadIdx.x * 4; i < ecnt; i += 1024) {
            int4 s4 = *(const int4*)(esrc + base + i);
            int4 d4 = *(const int4*)(edst + base + i);
            int ss[4] = {s4.x, s4.y, s4.z, s4.w};
            int dd[4] = {d4.x, d4.y, d4.z, d4.w};
#pragma unroll
            for (int j = 0; j < 4; ++j) {
                if ((unsigned)ss[j] - glo < (unsigned)GDIV) {
                    int pos = atomicAdd(cnt + ss[j], 1);
                    if (pos < SLOT)
                        csr16[(size_t)ss[j] * SLOT + pos] = (unsigned short)dd[j];
                }
            }
        }
        return;
    }

    int tid = threadIdx.x;
    int wid = tid >> 6, lane = tid & 63;
    int m = lane & 15, q = lane >> 4;
    int rowbase = blockIdx.x * 64 + wid * 16;
    int row = rowbase + m;

    half8 a[4];
    if (row < N_NODES) {
        if (F32IN) {
            const float* ar = (const float*)Ain + (size_t)row * D;
#pragma unroll
            for (int s = 0; s < 4; ++s) {
                float4 lo = *(const float4*)(ar + s * 32 + q * 8);
                float4 hi = *(const float4*)(ar + s * 32 + q * 8 + 4);
                a[s][0] = (_Float16)lo.x; a[s][1] = (_Float16)lo.y;
                a[s][2] = (_Float16)lo.z; a[s][3] = (_Float16)lo.w;
                a[s][4] = (_Float16)hi.x; a[s][5] = (_Float16)hi.y;
                a[s][6] = (_Float16)hi.z; a[s][7] = (_Float16)hi.w;
            }
        } else {
            const _Float16* ar = (const _Float16*)Ain + (size_t)row * D;
#pragma unroll
            for (int s = 0; s < 4; ++s)
                a[s] = *(const half8*)(ar + s * 32 + q * 8);
        }
    } else {
#pragma unroll
        for (int s = 0; s < 4; ++s)
#pragma unroll
            for (int j = 0; j < 8; ++j) a[s][j] = (_Float16)0.f;
    }

    f32x4 acc[8];
#pragma unroll
    for (int t = 0; t < 8; ++t) acc[t] = (f32x4)(0.f);

#pragma unroll
    for (int hh = 0; hh < 2; ++hh) {
        // stage output cols [hh*64, hh*64+64)
        for (int j = tid * 8; j < 64 * D; j += 2048) {
            int n = j >> 7, k = j & 127;
            *(half8*)(&Wl[n * 130 + k]) = *(const half8*)(Wt + (hh * 64 + n) * D + k);
        }
        __syncthreads();
#pragma unroll
        for (int s = 0; s < 4; ++s) {
#pragma unroll
            for (int t = 0; t < 4; ++t) {
                half8 bf = *(const half8*)(&Wl[(t * 16 + m) * 130 + s * 32 + q * 8]);
                acc[hh * 4 + t] = __builtin_amdgcn_mfma_f32_16x16x32_f16(a[s], bf, acc[hh * 4 + t], 0, 0, 0);
            }
        }
        __syncthreads();
    }

    float sp[4] = {0.f, 0.f, 0.f, 0.f};
#pragma unroll
    for (int t = 0; t < 8; ++t) {
        int col = t * 16 + m;
        float bc = b[col];
        float ac = awr[col];
#pragma unroll
        for (int r = 0; r < 4; ++r) {
            int orow = rowbase + q * 4 + r;
            float v = acc[t][r] + bc;
            v = v > 0.f ? v : 0.2f * v;
            sp[r] = fmaf(v, ac, sp[r]);
            if (orow < N_NODES)
                hout[(size_t)orow * D + col] = (_Float16)v;
        }
    }
#pragma unroll
    for (int r = 0; r < 4; ++r) {
#pragma unroll
        for (int o = 1; o < 16; o <<= 1)
            sp[r] += __shfl_xor(sp[r], o, 64);
    }
    if (m == 0) {
#pragma unroll
        for (int r = 0; r < 4; ++r) {
            int orow = rowbase + q * 4 + r;
            if (orow < N_NODES) sr[orow] = sp[r];
        }
    }
}

// ---------------------------------------------------------------------------
// Fused softmax + gather, one wave per node, h f16, fixed-slot csr u16.
// Dual-row: lanes 0-31 even edges, 32-63 odd edges; half4 (8B) per lane;
// unroll 8 edges -> 4 independent row loads in flight per half-wave.
// (byte-offset, alpha) pairs in LDS -> one ds_read_b64 per edge.
// ---------------------------------------------------------------------------
__global__ __launch_bounds__(256, 8) void gather_kernel(
    const int* __restrict__ cnt, const unsigned short* __restrict__ csr16,
    const float* __restrict__ sr, const _Float16* __restrict__ h,
    _Float16* __restrict__ out16, float* __restrict__ out32)
{
    __shared__ int plds[4][2 * SLOT + 8];
    int wid = threadIdx.x >> 6, lane = threadIdx.x & 63;
    int half = lane >> 5, sl = lane & 31;
    int n = blockIdx.x * 4 + wid;
    int deg = cnt[n];
    if (deg > SLOT) deg = SLOT;
    const unsigned short* ce = csr16 + (size_t)n * SLOT;
    int* prow = plds[wid];

    float ev[2];
    float m = -INFINITY;
#pragma unroll
    for (int t = 0; t < 2; ++t) {
        int k = t * 64 + lane;
        if (k < deg) {
            int d = ce[k];
            prow[2 * k] = d << 8;
            float e = sr[d];
            ev[t] = e;
            m = fmaxf(m, e);
        }
    }
    for (int o = 32; o > 0; o >>= 1) m = fmaxf(m, __shfl_xor(m, o, 64));

    float s = 0.f;
#pragma unroll
    for (int t = 0; t < 2; ++t) {
        int k = t * 64 + lane;
        if (k < deg) {
            float a = __expf(ev[t] - m);
            prow[2 * k + 1] = __float_as_int(a);
            s += a;
        }
    }
    for (int o = 32; o > 0; o >>= 1) s += __shfl_xor(s, o, 64);
    float inv = (deg > 0) ? 1.f / s : 0.f;

    float acc0 = 0.f, acc1 = 0.f, acc2 = 0.f, acc3 = 0.f;
    const char* hb = (const char*)h + sl * 8;
    int k = 0;
    int deg8 = deg & ~7;
    for (; k < deg8; k += 8) {
        int2 p0 = *(const int2*)(prow + 2 * (k + half));
        int2 p1 = *(const int2*)(prow + 2 * (k + 2 + half));
        int2 p2 = *(const int2*)(prow + 2 * (k + 4 + half));
        int2 p3 = *(const int2*)(prow + 2 * (k + 6 + half));
        half4 h0 = *(const half4*)(hb + p0.x);
        half4 h1 = *(const half4*)(hb + p1.x);
        half4 h2 = *(const half4*)(hb + p2.x);
        half4 h3 = *(const half4*)(hb + p3.x);
        float a0 = __int_as_float(p0.y);
        float a1 = __int_as_float(p1.y);
        float a2 = __int_as_float(p2.y);
        float a3 = __int_as_float(p3.y);
        acc0 = fmaf((float)h0[0], a0, acc0);
        acc1 = fmaf((float)h0[1], a0, acc1);
        acc2 = fmaf((float)h0[2], a0, acc2);
        acc3 = fmaf((float)h0[3], a0, acc3);
        acc0 = fmaf((float)h1[0], a1, acc0);
        acc1 = fmaf((float)h1[1], a1, acc1);
        acc2 = fmaf((float)h1[2], a1, acc2);
        acc3 = fmaf((float)h1[3], a1, acc3);
        acc0 = fmaf((float)h2[0], a2, acc0);
        acc1 = fmaf((float)h2[1], a2, acc1);
        acc2 = fmaf((float)h2[2], a2, acc2);
        acc3 = fmaf((float)h2[3], a2, acc3);
        acc0 = fmaf((float)h3[0], a3, acc0);
        acc1 = fmaf((float)h3[1], a3, acc1);
        acc2 = fmaf((float)h3[2], a3, acc2);
        acc3 = fmaf((float)h3[3], a3, acc3);
    }
    for (; k < deg; k += 2) {
        int kk = k + half;
        int2 p = (kk < deg) ? *(const int2*)(prow + 2 * kk) : make_int2(0, 0);
        half4 hv = *(const half4*)(hb + p.x);
        float a = __int_as_float(p.y);
        acc0 = fmaf((float)hv[0], a, acc0);
        acc1 = fmaf((float)hv[1], a, acc1);
        acc2 = fmaf((float)hv[2], a, acc2);
        acc3 = fmaf((float)hv[3], a, acc3);
    }

    acc0 += __shfl_xor(acc0, 32, 64);
    acc1 += __shfl_xor(acc1, 32, 64);
    acc2 += __shfl_xor(acc2, 32, 64);
    acc3 += __shfl_xor(acc3, 32, 64);

    if (half == 0) {
        float r0 = fmaxf(acc0 * inv, 0.f);
        float r1 = fmaxf(acc1 * inv, 0.f);
        float r2 = fmaxf(acc2 * inv, 0.f);
        float r3 = fmaxf(acc3 * inv, 0.f);
        if (out16) {
            half4 o;
            o[0] = (_Float16)r0; o[1] = (_Float16)r1;
            o[2] = (_Float16)r2; o[3] = (_Float16)r3;
            *(half4*)(out16 + (size_t)n * D + sl * 4) = o;
        } else {
            float4 o = make_float4(r0, r1, r2, r3);
            *(float4*)(out32 + (size_t)n * D + sl * 4) = o;
        }
    }
}

extern "C" void kernel_launch(void* const* d_in, const int* in_sizes, int n_in,
                              void* d_out, int out_size, void* d_ws, size_t ws_size,
                              hipStream_t stream)
{
    const float* x      = (const float*)d_in[0];
    const int*   esrc   = (const int*)d_in[1];
    const int*   edst   = (const int*)d_in[2];
    const float* lin_w  = (const float*)d_in[3];
    const float* lin_b  = (const float*)d_in[4];
    const float* attn_w = (const float*)d_in[5];
    float* out = (float*)d_out;

    char* ws = (char*)d_ws;
    _Float16*       h16A  = (_Float16*)(ws);                  // 12,800,000 B
    _Float16*       h16B  = (_Float16*)(ws + 12800000);       // 12,800,000 B
    float*          sr    = (float*)(ws + 25600000);          // 200,000 B
    int*            cnt   = (int*)(ws + 25800000);            // 200,000 B
    unsigned short* csr16 = (unsigned short*)(ws + 26000000); // 9,600,000 B
    _Float16*       Wt16  = (_Float16*)(ws + 35600000);       // 98,304 B

    // Prep: W transpose + cnt zero in one small kernel.
    prep_kernel<<<PREPB + CNTB, 256, 0, stream>>>(lin_w, Wt16, cnt);

    for (int l = 0; l < N_LAYERS; ++l) {
        bool last = (l == N_LAYERS - 1);
        if (l == 0)
            linear_mfma_kernel<true, true><<<LINB + NCHUNK * 8, 256, 0, stream>>>(
                x, Wt16, lin_b, attn_w + D, h16A, sr,
                esrc, edst, cnt, csr16);
        else
            linear_mfma_kernel<false, false><<<LINB, 256, 0, stream>>>(
                h16B, Wt16 + (size_t)l * D * D, lin_b + (size_t)l * D,
                attn_w + (size_t)l * 2 * D + D, h16A, sr,
                nullptr, nullptr, nullptr, nullptr);
        gather_kernel<<<N_NODES / 4, 256, 0, stream>>>(
            cnt, csr16, sr, h16A,
            last ? (_Float16*)nullptr : h16B, last ? out : nullptr);
    }
}

// Round 7
// 258.054 us; speedup vs baseline: 2.1497x; 1.0169x over previous
//
#include <hip/hip_runtime.h>
#include <math.h>

#define N_NODES 50000
#define N_EDGES 800000
#define D 128
#define N_LAYERS 3

#define FCHUNK 4096                              // edges per fill chunk (16/thread)
#define NCHUNK ((N_EDGES + FCHUNK - 1) / FCHUNK) // 196
#define GDIV 6250                                // src-ids per XCD group (8 groups)
#define SLOT 96                                  // csr slots per node (deg ~ Poisson(16))
#define PREPB ((N_LAYERS * D * D) / 256)         // 192 blocks for W transpose
#define CNTB ((N_NODES + 255) / 256)             // 196 blocks for cnt zero
#define LINB ((N_NODES + 63) / 64)               // 782 linear blocks

typedef _Float16 half8 __attribute__((ext_vector_type(8)));
typedef _Float16 half4 __attribute__((ext_vector_type(4)));
typedef float f32x4 __attribute__((ext_vector_type(4)));

// ---------------------------------------------------------------------------
// Prep: W transpose to f16 [l][n][k] + zero the degree counters.
// ---------------------------------------------------------------------------
__global__ __launch_bounds__(256) void prep_kernel(
    const float* __restrict__ W, _Float16* __restrict__ Wt, int* __restrict__ cnt)
{
    if (blockIdx.x < PREPB) {
        int idx = blockIdx.x * 256 + threadIdx.x;
        int l = idx >> 14, rem = idx & (D * D - 1);
        int k = rem >> 7, n = rem & 127;
        Wt[l * D * D + n * D + k] = (_Float16)W[idx];
    } else {
        int i = (blockIdx.x - PREPB) * 256 + threadIdx.x;
        if (i < N_NODES) cnt[i] = 0;
    }
}

// ---------------------------------------------------------------------------
// MFMA linear + fused sr:  hout = leaky_relu(A @ W + b);  sr[n] = hout[n].awr
// Block = 4 waves x 16 rows. W^T staged in TWO 64-col halves (16.6 KB LDS ->
// 6 blocks/CU). FUSEFILL (layer 0): blocks >= LINB run the XCD-partitioned
// CSR fill. [R6 measured: occupancy 62% (was 35%) but duration unchanged at
// ~49us -> fill is NOT occupancy-bound; likely memory-side atomic
// serialization. Structure kept as the best-measured config.]
// ---------------------------------------------------------------------------
template <bool F32IN, bool FUSEFILL>
__global__ __launch_bounds__(256, 6) void linear_mfma_kernel(
    const void* __restrict__ Ain, const _Float16* __restrict__ Wt,
    const float* __restrict__ b, const float* __restrict__ awr,
    _Float16* __restrict__ hout, float* __restrict__ sr,
    const int* __restrict__ esrc, const int* __restrict__ edst,
    int* __restrict__ cnt, unsigned short* __restrict__ csr16)
{
    __shared__ _Float16 Wl[64 * 130];  // 16,640 B

    if (FUSEFILL && blockIdx.x >= LINB) {
        int g = blockIdx.x & 7;
        int base = ((blockIdx.x - LINB) >> 3) * FCHUNK;
        int ecnt = N_EDGES - base;
        if (ecnt > FCHUNK) ecnt = FCHUNK;
        unsigned glo = (unsigned)(g * GDIV);
        for (int i = threadIdx.x * 4; i < ecnt; i += 1024) {
            int4 s4 = *(const int4*)(esrc + base + i);
            int4 d4 = *(const int4*)(edst + base + i);
            int ss[4] = {s4.x, s4.y, s4.z, s4.w};
            int dd[4] = {d4.x, d4.y, d4.z, d4.w};
#pragma unroll
            for (int j = 0; j < 4; ++j) {
                if ((unsigned)ss[j] - glo < (unsigned)GDIV) {
                    int pos = atomicAdd(cnt + ss[j], 1);
                    if (pos < SLOT)
                        csr16[(size_t)ss[j] * SLOT + pos] = (unsigned short)dd[j];
                }
            }
        }
        return;
    }

    int tid = threadIdx.x;
    int wid = tid >> 6, lane = tid & 63;
    int m = lane & 15, q = lane >> 4;
    int rowbase = blockIdx.x * 64 + wid * 16;
    int row = rowbase + m;

    half8 a[4];
    if (row < N_NODES) {
        if (F32IN) {
            const float* ar = (const float*)Ain + (size_t)row * D;
#pragma unroll
            for (int s = 0; s < 4; ++s) {
                float4 lo = *(const float4*)(ar + s * 32 + q * 8);
                float4 hi = *(const float4*)(ar + s * 32 + q * 8 + 4);
                a[s][0] = (_Float16)lo.x; a[s][1] = (_Float16)lo.y;
                a[s][2] = (_Float16)lo.z; a[s][3] = (_Float16)lo.w;
                a[s][4] = (_Float16)hi.x; a[s][5] = (_Float16)hi.y;
                a[s][6] = (_Float16)hi.z; a[s][7] = (_Float16)hi.w;
            }
        } else {
            const _Float16* ar = (const _Float16*)Ain + (size_t)row * D;
#pragma unroll
            for (int s = 0; s < 4; ++s)
                a[s] = *(const half8*)(ar + s * 32 + q * 8);
        }
    } else {
#pragma unroll
        for (int s = 0; s < 4; ++s)
#pragma unroll
            for (int j = 0; j < 8; ++j) a[s][j] = (_Float16)0.f;
    }

    f32x4 acc[8];
#pragma unroll
    for (int t = 0; t < 8; ++t) acc[t] = (f32x4)(0.f);

#pragma unroll
    for (int hh = 0; hh < 2; ++hh) {
        for (int j = tid * 8; j < 64 * D; j += 2048) {
            int n = j >> 7, k = j & 127;
            *(half8*)(&Wl[n * 130 + k]) = *(const half8*)(Wt + (hh * 64 + n) * D + k);
        }
        __syncthreads();
#pragma unroll
        for (int s = 0; s < 4; ++s) {
#pragma unroll
            for (int t = 0; t < 4; ++t) {
                half8 bf = *(const half8*)(&Wl[(t * 16 + m) * 130 + s * 32 + q * 8]);
                acc[hh * 4 + t] = __builtin_amdgcn_mfma_f32_16x16x32_f16(a[s], bf, acc[hh * 4 + t], 0, 0, 0);
            }
        }
        __syncthreads();
    }

    float sp[4] = {0.f, 0.f, 0.f, 0.f};
#pragma unroll
    for (int t = 0; t < 8; ++t) {
        int col = t * 16 + m;
        float bc = b[col];
        float ac = awr[col];
#pragma unroll
        for (int r = 0; r < 4; ++r) {
            int orow = rowbase + q * 4 + r;
            float v = acc[t][r] + bc;
            v = v > 0.f ? v : 0.2f * v;
            sp[r] = fmaf(v, ac, sp[r]);
            if (orow < N_NODES)
                hout[(size_t)orow * D + col] = (_Float16)v;
        }
    }
#pragma unroll
    for (int r = 0; r < 4; ++r) {
#pragma unroll
        for (int o = 1; o < 16; o <<= 1)
            sp[r] += __shfl_xor(sp[r], o, 64);
    }
    if (m == 0) {
#pragma unroll
        for (int r = 0; r < 4; ++r) {
            int orow = rowbase + q * 4 + r;
            if (orow < N_NODES) sr[orow] = sp[r];
        }
    }
}

// ---------------------------------------------------------------------------
// Fused softmax + gather, one wave per node. R7 restructure for load ILP:
// lane = (row r = lane>>4, col c = lane&15); each lane loads a 16B half8 of
// row dst[k+r] -> 4 rows per load instruction; unroll 4 -> 16 rows / 64B per
// lane in flight (was 8 rows / 32B with dual-row 8B loads). Theory: gather
// is LLC-latency-bound (205 MB random reads from 12.8MB table @ ~5 TB/s
// effective); 2x rows+bytes in flight should cut stall time.
// ---------------------------------------------------------------------------
__global__ __launch_bounds__(256, 8) void gather_kernel(
    const int* __restrict__ cnt, const unsigned short* __restrict__ csr16,
    const float* __restrict__ sr, const _Float16* __restrict__ h,
    _Float16* __restrict__ out16, float* __restrict__ out32)
{
    __shared__ int plds[4][2 * SLOT + 8];
    int wid = threadIdx.x >> 6, lane = threadIdx.x & 63;
    int r = lane >> 4, c = lane & 15;
    int n = blockIdx.x * 4 + wid;
    int deg = cnt[n];
    if (deg > SLOT) deg = SLOT;
    const unsigned short* ce = csr16 + (size_t)n * SLOT;
    int* prow = plds[wid];

    // --- softmax over this node's edges (slots 0..deg-1) ---
    float ev[2];
    float m = -INFINITY;
#pragma unroll
    for (int t = 0; t < 2; ++t) {
        int k = t * 64 + lane;
        if (k < deg) {
            int d = ce[k];
            prow[2 * k] = d << 8;            // byte offset of row d (d*256)
            float e = sr[d];
            ev[t] = e;
            m = fmaxf(m, e);
        }
    }
    for (int o = 32; o > 0; o >>= 1) m = fmaxf(m, __shfl_xor(m, o, 64));

    float s = 0.f;
#pragma unroll
    for (int t = 0; t < 2; ++t) {
        int k = t * 64 + lane;
        if (k < deg) {
            float a = __expf(ev[t] - m);
            prow[2 * k + 1] = __float_as_int(a);
            s += a;
        }
    }
    for (int o = 32; o > 0; o >>= 1) s += __shfl_xor(s, o, 64);
    float inv = (deg > 0) ? 1.f / s : 0.f;

    // --- weighted gather: 16B/lane, 4 rows per instr, 16 rows in flight ---
    float acc[8];
#pragma unroll
    for (int j = 0; j < 8; ++j) acc[j] = 0.f;
    const char* hb = (const char*)h + c * 16;

    int k = 0;
    int degU = deg & ~15;
    for (; k < degU; k += 16) {
        int2 p0 = *(const int2*)(prow + 2 * (k + r));
        int2 p1 = *(const int2*)(prow + 2 * (k + 4 + r));
        int2 p2 = *(const int2*)(prow + 2 * (k + 8 + r));
        int2 p3 = *(const int2*)(prow + 2 * (k + 12 + r));
        half8 h0 = *(const half8*)(hb + p0.x);
        half8 h1 = *(const half8*)(hb + p1.x);
        half8 h2 = *(const half8*)(hb + p2.x);
        half8 h3 = *(const half8*)(hb + p3.x);
        float a0 = __int_as_float(p0.y);
        float a1 = __int_as_float(p1.y);
        float a2 = __int_as_float(p2.y);
        float a3 = __int_as_float(p3.y);
#pragma unroll
        for (int j = 0; j < 8; ++j) acc[j] = fmaf((float)h0[j], a0, acc[j]);
#pragma unroll
        for (int j = 0; j < 8; ++j) acc[j] = fmaf((float)h1[j], a1, acc[j]);
#pragma unroll
        for (int j = 0; j < 8; ++j) acc[j] = fmaf((float)h2[j], a2, acc[j]);
#pragma unroll
        for (int j = 0; j < 8; ++j) acc[j] = fmaf((float)h3[j], a3, acc[j]);
    }
    for (; k < deg; k += 4) {
        int kk = k + r;
        int2 p = (kk < deg) ? *(const int2*)(prow + 2 * kk) : make_int2(0, 0);
        half8 hv = *(const half8*)(hb + p.x);
        float a = __int_as_float(p.y);
#pragma unroll
        for (int j = 0; j < 8; ++j) acc[j] = fmaf((float)hv[j], a, acc[j]);
    }

    // reduce across the 4 row-groups (lane stride 16)
#pragma unroll
    for (int j = 0; j < 8; ++j) {
        acc[j] += __shfl_xor(acc[j], 16, 64);
        acc[j] += __shfl_xor(acc[j], 32, 64);
    }

    if (r == 0) {  // lanes 0..15 hold the full row, 8 dims each
        float rv[8];
#pragma unroll
        for (int j = 0; j < 8; ++j) rv[j] = fmaxf(acc[j] * inv, 0.f);
        if (out16) {
            half8 o;
#pragma unroll
            for (int j = 0; j < 8; ++j) o[j] = (_Float16)rv[j];
            *(half8*)(out16 + (size_t)n * D + c * 8) = o;
        } else {
            float4 lo = make_float4(rv[0], rv[1], rv[2], rv[3]);
            float4 hi = make_float4(rv[4], rv[5], rv[6], rv[7]);
            *(float4*)(out32 + (size_t)n * D + c * 8) = lo;
            *(float4*)(out32 + (size_t)n * D + c * 8 + 4) = hi;
        }
    }
}

extern "C" void kernel_launch(void* const* d_in, const int* in_sizes, int n_in,
                              void* d_out, int out_size, void* d_ws, size_t ws_size,
                              hipStream_t stream)
{
    const float* x      = (const float*)d_in[0];
    const int*   esrc   = (const int*)d_in[1];
    const int*   edst   = (const int*)d_in[2];
    const float* lin_w  = (const float*)d_in[3];
    const float* lin_b  = (const float*)d_in[4];
    const float* attn_w = (const float*)d_in[5];
    float* out = (float*)d_out;

    char* ws = (char*)d_ws;
    _Float16*       h16A  = (_Float16*)(ws);                  // 12,800,000 B
    _Float16*       h16B  = (_Float16*)(ws + 12800000);       // 12,800,000 B
    float*          sr    = (float*)(ws + 25600000);          // 200,000 B
    int*            cnt   = (int*)(ws + 25800000);            // 200,000 B
    unsigned short* csr16 = (unsigned short*)(ws + 26000000); // 9,600,000 B
    _Float16*       Wt16  = (_Float16*)(ws + 35600000);       // 98,304 B

    // Prep: W transpose + cnt zero in one small kernel.
    prep_kernel<<<PREPB + CNTB, 256, 0, stream>>>(lin_w, Wt16, cnt);

    for (int l = 0; l < N_LAYERS; ++l) {
        bool last = (l == N_LAYERS - 1);
        if (l == 0)
            linear_mfma_kernel<true, true><<<LINB + NCHUNK * 8, 256, 0, stream>>>(
                x, Wt16, lin_b, attn_w + D, h16A, sr,
                esrc, edst, cnt, csr16);
        else
            linear_mfma_kernel<false, false><<<LINB, 256, 0, stream>>>(
                h16B, Wt16 + (size_t)l * D * D, lin_b + (size_t)l * D,
                attn_w + (size_t)l * 2 * D + D, h16A, sr,
                nullptr, nullptr, nullptr, nullptr);
        gather_kernel<<<N_NODES / 4, 256, 0, stream>>>(
            cnt, csr16, sr, h16A,
            last ? (_Float16*)nullptr : h16B, last ? out : nullptr);
    }
}